// Round 4
// 645.142 us; speedup vs baseline: 1.0016x; 1.0016x over previous
//
#include <hip/hip_runtime.h>
#include <math.h>

#define B 8192
#define FA 848
#define FB 600
#define FC 264
#define ND 13
#define F 1725
#define KP1 1728   // F padded to multiple of 32
#define N1 1024
#define N2 512
#define N3 256
#define EPS 1e-5f
#define GROWS 16   // rows per gather_stats block

typedef __attribute__((ext_vector_type(4))) float f32x4;
typedef __attribute__((ext_vector_type(8))) short bf16x8;
typedef unsigned short u16;
typedef unsigned int u32;

__device__ __forceinline__ u16 f2bf(float x) {
  u32 b = __builtin_bit_cast(u32, x);
  u32 r = (b + 0x7fffu + ((b >> 16) & 1u)) >> 16;
  return (u16)r;
}
__device__ __forceinline__ float bf2f(u16 h) {
  return __builtin_bit_cast(float, (u32)h << 16);
}

// ---------------- gather + concat + fused column stats ----------------
__global__ __launch_bounds__(256) void gather_stats_kernel(
    const int* __restrict__ sparse, const float* __restrict__ dense,
    const float* __restrict__ ea, const float* __restrict__ eb,
    const float* __restrict__ ec, float* __restrict__ h,
    float* __restrict__ sums) {
  int r0 = blockIdx.x * GROWS;
  int tid = threadIdx.x;
  __shared__ int sp_s[GROWS][26];
  for (int t = tid; t < GROWS * 26; t += 256)
    sp_s[t / 26][t % 26] = sparse[(r0 + t / 26) * 26 + t % 26];
  __syncthreads();
  float s[7], ss[7];
#pragma unroll
  for (int q = 0; q < 7; ++q) { s[q] = 0.f; ss[q] = 0.f; }
  for (int rr = 0; rr < GROWS; ++rr) {
    int r = r0 + rr;
    const int* sp = sp_s[rr];
    float* hr = h + (size_t)r * F;
    int it = 0;
    for (int j = tid; j < F; j += 256, ++it) {
      float v;
      if (j < FA) {
        int t = j / 106, c = j - t * 106;
        v = ea[(size_t)t * 10600000 + (size_t)sp[t] * 106 + c];
      } else if (j < FA + FB) {
        int jj = j - FA; int t = jj / 60, c = jj - t * 60;
        v = eb[(size_t)t * 600000 + (size_t)sp[8 + t] * 60 + c];
      } else if (j < FA + FB + FC) {
        int jj = j - FA - FB; int t = jj / 33, c = jj - t * 33;
        v = ec[(size_t)t * 33000 + (size_t)sp[18 + t] * 33 + c];
      } else {
        v = dense[r * ND + (j - (FA + FB + FC))];
      }
      hr[j] = v;
      s[it] += v; ss[it] += v * v;
    }
  }
#pragma unroll
  for (int q = 0; q < 7; ++q) {
    int j = q * 256 + tid;
    if (j < F) {
      atomicAdd(&sums[j], s[q]);
      atomicAdd(&sums[F + j], ss[q]);
    }
  }
}

// ---------------- prep: finstat(F) + recurrence constants ----------------
__global__ __launch_bounds__(256) void prep_kernel(
    const float* __restrict__ sums, const float* __restrict__ cw,
    const float* __restrict__ cb, const float* __restrict__ wout,
    float* __restrict__ mi, float* __restrict__ consts) {
  int tid = threadIdx.x;
  float acc[4] = {0.f, 0.f, 0.f, 0.f};  // d1, d2, d3, e
  for (int j = tid; j < F; j += 256) {
    float m = sums[j] * (1.0f / B);
    float v = sums[F + j] * (1.0f / B) - m * m;
    float inv = rsqrtf(v + EPS);
    mi[j] = m;
    mi[F + j] = inv;
    float c1 = cb[j];
    float c2 = c1 + cb[F + j];
    float c3 = c2 + cb[2 * F + j];
    float c4 = c3 + cb[3 * F + j];
    acc[0] += c1 * cw[F + j];
    acc[1] += c2 * cw[2 * F + j];
    acc[2] += c3 * cw[3 * F + j];
    acc[3] += c4 * wout[j];
  }
  __shared__ float red[4][4];
  int lane = tid & 63, wid = tid >> 6;
#pragma unroll
  for (int q = 0; q < 4; ++q) {
    float v = acc[q];
    for (int off = 32; off; off >>= 1) v += __shfl_down(v, off, 64);
    if (lane == 0) red[q][wid] = v;
  }
  __syncthreads();
  if (tid == 0) {
    consts[0] = 0.f;
    consts[1] = red[0][0] + red[0][1] + red[0][2] + red[0][3];
    consts[2] = red[1][0] + red[1][1] + red[1][2] + red[1][3];
    consts[3] = red[2][0] + red[2][1] + red[2][2] + red[2][3];
    consts[4] = red[3][0] + red[3][1] + red[3][2] + red[3][3];
  }
}

// ---------------- fused: BN-apply h -> hbf (bf16) + cross GEMV + recurrence ----
__global__ __launch_bounds__(256) void bnapply_gemv_kernel(
    const float* __restrict__ h, const float* __restrict__ mi,
    const float* __restrict__ cw, const float* __restrict__ wout,
    const float* __restrict__ consts, u32* __restrict__ hbf,
    float* __restrict__ cpart) {
  int r = blockIdx.x, tid = threadIdx.x;
  const float* xr = h + (size_t)r * F;
  u32* br = hbf + (size_t)r * (KP1 / 2);
  float p[5] = {0.f, 0.f, 0.f, 0.f, 0.f};
  for (int jj = tid; jj < KP1 / 2; jj += 256) {
    int c0 = jj * 2, c1 = c0 + 1;
    float x0 = 0.f, x1 = 0.f;
    if (c0 < F) x0 = (xr[c0] - mi[c0]) * mi[F + c0];
    if (c1 < F) x1 = (xr[c1] - mi[c1]) * mi[F + c1];
    br[jj] = (u32)f2bf(x0) | ((u32)f2bf(x1) << 16);
    if (c0 < F) {
      p[0] += x0 * cw[c0];
      p[1] += x0 * cw[F + c0];
      p[2] += x0 * cw[2 * F + c0];
      p[3] += x0 * cw[3 * F + c0];
      p[4] += x0 * wout[c0];
    }
    if (c1 < F) {
      p[0] += x1 * cw[c1];
      p[1] += x1 * cw[F + c1];
      p[2] += x1 * cw[2 * F + c1];
      p[3] += x1 * cw[3 * F + c1];
      p[4] += x1 * wout[c1];
    }
  }
  __shared__ float red[5][4];
  int lane = tid & 63, wid = tid >> 6;
#pragma unroll
  for (int i = 0; i < 5; ++i) {
    float v = p[i];
    for (int off = 32; off; off >>= 1) v += __shfl_down(v, off, 64);
    if (lane == 0) red[i][wid] = v;
  }
  __syncthreads();
  if (tid == 0) {
    float u[5];
#pragma unroll
    for (int i = 0; i < 5; ++i)
      u[i] = red[i][0] + red[i][1] + red[i][2] + red[i][3];
    float a = 1.f;
#pragma unroll
    for (int i = 0; i < 4; ++i) {
      float sv = a * u[i] + consts[i];
      a += sv;
    }
    cpart[r] = a * u[4] + consts[4];
  }
}

// ---------------- all three W[K][N] -> Wt[N][Kp] bf16 transposes in one launch --
__global__ __launch_bounds__(256) void convw_all_kernel(
    const float* __restrict__ W1, const float* __restrict__ W2,
    const float* __restrict__ W3, u16* __restrict__ W1t,
    u16* __restrict__ W2t, u16* __restrict__ W3t) {
  int b = blockIdx.x;
  const float* W; u16* Wt; int K, N, Kp, bx, by;
  if (b < 1728) {          // N1/32=32 x, KP1/32=54 y
    W = W1; Wt = W1t; K = F;  N = N1; Kp = KP1; bx = b & 31; by = b >> 5;
  } else if (b < 2240) {   // N2/32=16 x, N1/32=32 y
    b -= 1728;
    W = W2; Wt = W2t; K = N1; N = N2; Kp = N1;  bx = b & 15; by = b >> 4;
  } else {                 // N3/32=8 x, N2/32=16 y
    b -= 2240;
    W = W3; Wt = W3t; K = N2; N = N3; Kp = N2;  bx = b & 7;  by = b >> 3;
  }
  __shared__ float t[32][33];
  int n0 = bx * 32, k0 = by * 32;
  int tx = threadIdx.x, ty = threadIdx.y;  // 32 x 8
#pragma unroll
  for (int i = 0; i < 4; ++i) {
    int k = k0 + ty + i * 8;
    t[ty + i * 8][tx] = (k < K) ? W[(size_t)k * N + n0 + tx] : 0.f;
  }
  __syncthreads();
#pragma unroll
  for (int i = 0; i < 4; ++i) {
    int n = n0 + ty + i * 8;
    Wt[(size_t)n * Kp + k0 + tx] = f2bf(t[tx][ty + i * 8]);
  }
}

// ---------------- bf16 MFMA GEMM + fused column-stats epilogue ----------------
template <bool OUT_BF>
__global__ __launch_bounds__(256) void gemm_bf16_kernel(
    const u16* __restrict__ A, const u16* __restrict__ Bt,
    void* __restrict__ Cout, float* __restrict__ gsum, int N, int K) {
  __shared__ u16 As[128 * 32];
  __shared__ u16 Bs[128 * 32];
  int tid = threadIdx.x;
  int lane = tid & 63;
  int wave = tid >> 6;
  int row0 = blockIdx.y * 128, col0 = blockIdx.x * 128;
  int wm = (wave >> 1) * 64, wn = (wave & 1) * 64;
  int mrow = lane & 15;
  int kq = lane >> 4;

  f32x4 acc[4][4];
#pragma unroll
  for (int i = 0; i < 4; ++i)
#pragma unroll
    for (int j = 0; j < 4; ++j) acc[i][j] = (f32x4){0.f, 0.f, 0.f, 0.f};

  int kc = (tid & 3) * 8;
  const u16* Ag = A + (size_t)row0 * K;
  const u16* Bg = Bt + (size_t)col0 * K;

  for (int k0 = 0; k0 < K; k0 += 32) {
#pragma unroll
    for (int i = 0; i < 2; ++i) {
      int u = i * 256 + tid;
      int rr = u >> 2;
      __builtin_amdgcn_global_load_lds(
          (const __attribute__((address_space(1))) u32*)(Ag + (size_t)rr * K + k0 + kc),
          (__attribute__((address_space(3))) u32*)(As + u * 8), 16, 0, 0);
      __builtin_amdgcn_global_load_lds(
          (const __attribute__((address_space(1))) u32*)(Bg + (size_t)rr * K + k0 + kc),
          (__attribute__((address_space(3))) u32*)(Bs + u * 8), 16, 0, 0);
    }
    __syncthreads();
    bf16x8 af[4], bfr[4];
#pragma unroll
    for (int mi = 0; mi < 4; ++mi)
      af[mi] = *(const bf16x8*)(As + (wm + mi * 16 + mrow) * 32 + kq * 8);
#pragma unroll
    for (int ni = 0; ni < 4; ++ni)
      bfr[ni] = *(const bf16x8*)(Bs + (wn + ni * 16 + mrow) * 32 + kq * 8);
#pragma unroll
    for (int mi = 0; mi < 4; ++mi)
#pragma unroll
      for (int ni = 0; ni < 4; ++ni)
        acc[mi][ni] = __builtin_amdgcn_mfma_f32_16x16x32_bf16(
            af[mi], bfr[ni], acc[mi][ni], 0, 0, 0);
    __syncthreads();
  }

  float* sred = (float*)As;  // 256 floats: [0..127]=sum, [128..255]=sumsq
  sred[tid] = 0.f;
  __syncthreads();
#pragma unroll
  for (int ni = 0; ni < 4; ++ni) {
    int col_l = wn + ni * 16 + mrow;
    int col = col0 + col_l;
    float s = 0.f, ss = 0.f;
#pragma unroll
    for (int mi = 0; mi < 4; ++mi) {
#pragma unroll
      for (int reg = 0; reg < 4; ++reg) {
        int row = row0 + wm + mi * 16 + kq * 4 + reg;
        float v = acc[mi][ni][reg];
        if (OUT_BF) {
          u16 hb = f2bf(v);
          v = bf2f(hb);
          ((u16*)Cout)[(size_t)row * N + col] = hb;
        } else {
          ((float*)Cout)[(size_t)row * N + col] = v;
        }
        s += v;
        ss += v * v;
      }
    }
    s += __shfl_xor(s, 16, 64);  s += __shfl_xor(s, 32, 64);
    ss += __shfl_xor(ss, 16, 64); ss += __shfl_xor(ss, 32, 64);
    if (kq == 0) {
      atomicAdd(&sred[col_l], s);
      atomicAdd(&sred[128 + col_l], ss);
    }
  }
  __syncthreads();
  if (tid < 128) {
    atomicAdd(&gsum[col0 + tid], sred[tid]);
    atomicAdd(&gsum[N + col0 + tid], sred[128 + tid]);
  }
}

// ---------------- BN (from raw sums) + relu, bf16 -> bf16, 8 elems/thread ------
__global__ __launch_bounds__(256) void bn_relu_bb_kernel(
    const uint4* __restrict__ X, const float* __restrict__ sums,
    uint4* __restrict__ out, int Cmask, int total8) {
  int i = blockIdx.x * 256 + threadIdx.x;
  if (i >= total8) return;
  uint4 v = X[i];
  int colb = (i << 3) & Cmask;
  int C = Cmask + 1;
  const float invB = 1.0f / B;
  u32 w[4] = {v.x, v.y, v.z, v.w};
  u32 o[4];
#pragma unroll
  for (int e = 0; e < 4; ++e) {
    int c0 = colb + e * 2, c1 = c0 + 1;
    float m0 = sums[c0] * invB, m1 = sums[c1] * invB;
    float i0 = rsqrtf(sums[C + c0] * invB - m0 * m0 + EPS);
    float i1 = rsqrtf(sums[C + c1] * invB - m1 * m1 + EPS);
    float x0 = bf2f((u16)(w[e] & 0xffffu));
    float x1 = bf2f((u16)(w[e] >> 16));
    x0 = fmaxf((x0 - m0) * i0, 0.f);
    x1 = fmaxf((x1 - m1) * i1, 0.f);
    o[e] = (u32)f2bf(x0) | ((u32)f2bf(x1) << 16);
  }
  out[i] = make_uint4(o[0], o[1], o[2], o[3]);
}

// ---------------- fused final: BN(z3 from sums) + relu + dot Wout + sigmoid ----
__global__ __launch_bounds__(256) void final_kernel(
    const float* __restrict__ cpart, const float* __restrict__ z3,
    const float* __restrict__ sums, const float* __restrict__ wout,
    float* __restrict__ out) {
  int r = blockIdx.x, tid = threadIdx.x;  // tid = column, N3 = 256
  const float invB = 1.0f / B;
  float m = sums[tid] * invB;
  float inv = rsqrtf(sums[N3 + tid] * invB - m * m + EPS);
  float x = fmaxf((z3[(size_t)r * N3 + tid] - m) * inv, 0.f) * wout[F + tid];
  for (int off = 32; off; off >>= 1) x += __shfl_down(x, off, 64);
  __shared__ float red[4];
  int lane = tid & 63, wid = tid >> 6;
  if (lane == 0) red[wid] = x;
  __syncthreads();
  if (tid == 0) {
    float s = cpart[r] + red[0] + red[1] + red[2] + red[3];
    out[r] = 1.0f / (1.0f + expf(-s));
  }
}

extern "C" void kernel_launch(void* const* d_in, const int* in_sizes, int n_in,
                              void* d_out, int out_size, void* d_ws,
                              size_t ws_size, hipStream_t stream) {
  const int* sparse = (const int*)d_in[0];
  const float* dense = (const float*)d_in[1];
  const float* ea = (const float*)d_in[2];
  const float* eb = (const float*)d_in[3];
  const float* ec = (const float*)d_in[4];
  const float* cw = (const float*)d_in[5];
  const float* cb = (const float*)d_in[6];
  const float* W1 = (const float*)d_in[7];
  const float* W2 = (const float*)d_in[9];
  const float* W3 = (const float*)d_in[11];
  const float* Wout = (const float*)d_in[13];
  float* out = (float*)d_out;

  float* ws = (float*)d_ws;
  size_t o = 0;
  float* h = ws + o;      o += (size_t)B * F;        // 56.5 MB fp32
  float* z3 = ws + o;     o += (size_t)B * N3;       //  8.4 MB fp32
  float* cpart = ws + o;  o += B;
  float* stats = ws + o;  o += 8192;                 // all atomic stat buffers
  float* sumsF = stats;            // 2*F  = 3450
  float* g1 = stats + 3456;        // 2*N1 = 2048
  float* g2 = stats + 5504;        // 2*N2 = 1024
  float* g3 = stats + 6528;        // 2*N3 = 512
  float* mi = ws + o;     o += 3456;                 // mean/inv for F
  float* consts = ws + o; o += 16;  o = (o + 7) & ~(size_t)7;
  u16* hbf = (u16*)(ws + o);  o += (size_t)B * KP1 / 2;
  u16* z1 = (u16*)(ws + o);   o += (size_t)B * N1 / 2;
  u16* z1n = (u16*)(ws + o);  o += (size_t)B * N1 / 2;
  u16* z2 = (u16*)(ws + o);   o += (size_t)B * N2 / 2;
  u16* z2n = (u16*)(ws + o);  o += (size_t)B * N2 / 2;
  u16* W1t = (u16*)(ws + o);  o += (size_t)N1 * KP1 / 2;
  u16* W2t = (u16*)(ws + o);  o += (size_t)N2 * N1 / 2;
  u16* W3t = (u16*)(ws + o);  o += (size_t)N3 * N2 / 2;

  // one memset clears every atomic accumulator
  hipMemsetAsync(stats, 0, 8192 * sizeof(float), stream);

  convw_all_kernel<<<2368, dim3(32, 8), 0, stream>>>(W1, W2, W3, W1t, W2t, W3t);

  gather_stats_kernel<<<B / GROWS, 256, 0, stream>>>(sparse, dense, ea, eb, ec,
                                                     h, sumsF);
  prep_kernel<<<1, 256, 0, stream>>>(sumsF, cw, cb, Wout, mi, consts);
  bnapply_gemv_kernel<<<B, 256, 0, stream>>>(h, mi, cw, Wout, consts,
                                             (u32*)hbf, cpart);

  gemm_bf16_kernel<true><<<dim3(N1 / 128, B / 128), 256, 0, stream>>>(
      hbf, W1t, (void*)z1, g1, N1, KP1);
  bn_relu_bb_kernel<<<(B * N1 / 8 + 255) / 256, 256, 0, stream>>>(
      (const uint4*)z1, g1, (uint4*)z1n, N1 - 1, B * N1 / 8);

  gemm_bf16_kernel<true><<<dim3(N2 / 128, B / 128), 256, 0, stream>>>(
      z1n, W2t, (void*)z2, g2, N2, N1);
  bn_relu_bb_kernel<<<(B * N2 / 8 + 255) / 256, 256, 0, stream>>>(
      (const uint4*)z2, g2, (uint4*)z2n, N2 - 1, B * N2 / 8);

  gemm_bf16_kernel<false><<<dim3(N3 / 128, B / 128), 256, 0, stream>>>(
      z2n, W3t, (void*)z3, g3, N3, N2);

  final_kernel<<<B, 256, 0, stream>>>(cpart, z3, g3, Wout, out);
}

// Round 5
// 639.996 us; speedup vs baseline: 1.0096x; 1.0080x over previous
//
#include <hip/hip_runtime.h>
#include <math.h>

#define B 8192
#define FA 848
#define FB 600
#define FC 264
#define ND 13
#define F 1725
#define KP1 1728   // F padded to multiple of 32
#define N1 1024
#define N2 512
#define N3 256
#define EPS 1e-5f
#define GROWS 16   // rows per gather_stats block

typedef __attribute__((ext_vector_type(4))) float f32x4;
typedef __attribute__((ext_vector_type(8))) short bf16x8;
typedef unsigned short u16;
typedef unsigned int u32;

__device__ __forceinline__ u16 f2bf(float x) {
  u32 b = __builtin_bit_cast(u32, x);
  u32 r = (b + 0x7fffu + ((b >> 16) & 1u)) >> 16;
  return (u16)r;
}
__device__ __forceinline__ float bf2f(u16 h) {
  return __builtin_bit_cast(float, (u32)h << 16);
}

// ---------------- gather + concat + fused column stats ----------------
__global__ __launch_bounds__(256) void gather_stats_kernel(
    const int* __restrict__ sparse, const float* __restrict__ dense,
    const float* __restrict__ ea, const float* __restrict__ eb,
    const float* __restrict__ ec, float* __restrict__ h,
    float* __restrict__ sums) {
  int r0 = blockIdx.x * GROWS;
  int tid = threadIdx.x;
  __shared__ int sp_s[GROWS][26];
  for (int t = tid; t < GROWS * 26; t += 256)
    sp_s[t / 26][t % 26] = sparse[(r0 + t / 26) * 26 + t % 26];
  __syncthreads();
  float s[7], ss[7];
#pragma unroll
  for (int q = 0; q < 7; ++q) { s[q] = 0.f; ss[q] = 0.f; }
  for (int rr = 0; rr < GROWS; ++rr) {
    int r = r0 + rr;
    const int* sp = sp_s[rr];
    float* hr = h + (size_t)r * F;
    int it = 0;
    for (int j = tid; j < F; j += 256, ++it) {
      float v;
      if (j < FA) {
        int t = j / 106, c = j - t * 106;
        v = ea[(size_t)t * 10600000 + (size_t)sp[t] * 106 + c];
      } else if (j < FA + FB) {
        int jj = j - FA; int t = jj / 60, c = jj - t * 60;
        v = eb[(size_t)t * 600000 + (size_t)sp[8 + t] * 60 + c];
      } else if (j < FA + FB + FC) {
        int jj = j - FA - FB; int t = jj / 33, c = jj - t * 33;
        v = ec[(size_t)t * 33000 + (size_t)sp[18 + t] * 33 + c];
      } else {
        v = dense[r * ND + (j - (FA + FB + FC))];
      }
      hr[j] = v;
      s[it] += v; ss[it] += v * v;
    }
  }
#pragma unroll
  for (int q = 0; q < 7; ++q) {
    int j = q * 256 + tid;
    if (j < F) {
      atomicAdd(&sums[j], s[q]);
      atomicAdd(&sums[F + j], ss[q]);
    }
  }
}

// ---------------- prep: finstat(F) + recurrence constants ----------------
__global__ __launch_bounds__(256) void prep_kernel(
    const float* __restrict__ sums, const float* __restrict__ cw,
    const float* __restrict__ cb, const float* __restrict__ wout,
    float* __restrict__ mi, float* __restrict__ consts) {
  int tid = threadIdx.x;
  float acc[4] = {0.f, 0.f, 0.f, 0.f};  // d1, d2, d3, e
  for (int j = tid; j < F; j += 256) {
    float m = sums[j] * (1.0f / B);
    float v = sums[F + j] * (1.0f / B) - m * m;
    float inv = rsqrtf(v + EPS);
    mi[j] = m;
    mi[F + j] = inv;
    float c1 = cb[j];
    float c2 = c1 + cb[F + j];
    float c3 = c2 + cb[2 * F + j];
    float c4 = c3 + cb[3 * F + j];
    acc[0] += c1 * cw[F + j];
    acc[1] += c2 * cw[2 * F + j];
    acc[2] += c3 * cw[3 * F + j];
    acc[3] += c4 * wout[j];
  }
  __shared__ float red[4][4];
  int lane = tid & 63, wid = tid >> 6;
#pragma unroll
  for (int q = 0; q < 4; ++q) {
    float v = acc[q];
    for (int off = 32; off; off >>= 1) v += __shfl_down(v, off, 64);
    if (lane == 0) red[q][wid] = v;
  }
  __syncthreads();
  if (tid == 0) {
    consts[0] = 0.f;
    consts[1] = red[0][0] + red[0][1] + red[0][2] + red[0][3];
    consts[2] = red[1][0] + red[1][1] + red[1][2] + red[1][3];
    consts[3] = red[2][0] + red[2][1] + red[2][2] + red[2][3];
    consts[4] = red[3][0] + red[3][1] + red[3][2] + red[3][3];
  }
}

// ---------------- fused: BN-apply h -> hbf (bf16) + cross GEMV + recurrence ----
__global__ __launch_bounds__(256) void bnapply_gemv_kernel(
    const float* __restrict__ h, const float* __restrict__ mi,
    const float* __restrict__ cw, const float* __restrict__ wout,
    const float* __restrict__ consts, u32* __restrict__ hbf,
    float* __restrict__ cpart) {
  int r = blockIdx.x, tid = threadIdx.x;
  const float* xr = h + (size_t)r * F;
  u32* br = hbf + (size_t)r * (KP1 / 2);
  float p[5] = {0.f, 0.f, 0.f, 0.f, 0.f};
  for (int jj = tid; jj < KP1 / 2; jj += 256) {
    int c0 = jj * 2, c1 = c0 + 1;
    float x0 = 0.f, x1 = 0.f;
    if (c0 < F) x0 = (xr[c0] - mi[c0]) * mi[F + c0];
    if (c1 < F) x1 = (xr[c1] - mi[c1]) * mi[F + c1];
    br[jj] = (u32)f2bf(x0) | ((u32)f2bf(x1) << 16);
    if (c0 < F) {
      p[0] += x0 * cw[c0];
      p[1] += x0 * cw[F + c0];
      p[2] += x0 * cw[2 * F + c0];
      p[3] += x0 * cw[3 * F + c0];
      p[4] += x0 * wout[c0];
    }
    if (c1 < F) {
      p[0] += x1 * cw[c1];
      p[1] += x1 * cw[F + c1];
      p[2] += x1 * cw[2 * F + c1];
      p[3] += x1 * cw[3 * F + c1];
      p[4] += x1 * wout[c1];
    }
  }
  __shared__ float red[5][4];
  int lane = tid & 63, wid = tid >> 6;
#pragma unroll
  for (int i = 0; i < 5; ++i) {
    float v = p[i];
    for (int off = 32; off; off >>= 1) v += __shfl_down(v, off, 64);
    if (lane == 0) red[i][wid] = v;
  }
  __syncthreads();
  if (tid == 0) {
    float u[5];
#pragma unroll
    for (int i = 0; i < 5; ++i)
      u[i] = red[i][0] + red[i][1] + red[i][2] + red[i][3];
    float a = 1.f;
#pragma unroll
    for (int i = 0; i < 4; ++i) {
      float sv = a * u[i] + consts[i];
      a += sv;
    }
    cpart[r] = a * u[4] + consts[4];
  }
}

// ---------------- all three W[K][N] -> Wt[N][Kp] bf16 transposes in one launch --
__global__ __launch_bounds__(256) void convw_all_kernel(
    const float* __restrict__ W1, const float* __restrict__ W2,
    const float* __restrict__ W3, u16* __restrict__ W1t,
    u16* __restrict__ W2t, u16* __restrict__ W3t) {
  int b = blockIdx.x;
  const float* W; u16* Wt; int K, N, Kp, bx, by;
  if (b < 1728) {          // N1/32=32 x, KP1/32=54 y
    W = W1; Wt = W1t; K = F;  N = N1; Kp = KP1; bx = b & 31; by = b >> 5;
  } else if (b < 2240) {   // N2/32=16 x, N1/32=32 y
    b -= 1728;
    W = W2; Wt = W2t; K = N1; N = N2; Kp = N1;  bx = b & 15; by = b >> 4;
  } else {                 // N3/32=8 x, N2/32=16 y
    b -= 2240;
    W = W3; Wt = W3t; K = N2; N = N3; Kp = N2;  bx = b & 7;  by = b >> 3;
  }
  __shared__ float t[32][33];
  int n0 = bx * 32, k0 = by * 32;
  int tx = threadIdx.x, ty = threadIdx.y;  // 32 x 8
#pragma unroll
  for (int i = 0; i < 4; ++i) {
    int k = k0 + ty + i * 8;
    t[ty + i * 8][tx] = (k < K) ? W[(size_t)k * N + n0 + tx] : 0.f;
  }
  __syncthreads();
#pragma unroll
  for (int i = 0; i < 4; ++i) {
    int n = n0 + ty + i * 8;
    Wt[(size_t)n * Kp + k0 + tx] = f2bf(t[tx][ty + i * 8]);
  }
}

// ---------------- bf16 MFMA GEMM + fused column-stats epilogue ----------------
// TM = row-tile (64 or 128); N-tile fixed at 128.
// TM=64 doubles the grid for the narrow-N GEMMs (2 blocks/CU instead of 1,
// so barrier/vmcnt drains overlap across co-resident blocks).
template <bool OUT_BF, int TM>
__global__ __launch_bounds__(256) void gemm_bf16_kernel(
    const u16* __restrict__ A, const u16* __restrict__ Bt,
    void* __restrict__ Cout, float* __restrict__ gsum, int N, int K) {
  constexpr int MI = TM / 32;          // A-frag repeats per wave (m-dir)
  __shared__ u16 As[TM * 32];
  __shared__ u16 Bs[128 * 32];
  int tid = threadIdx.x;
  int lane = tid & 63;
  int wave = tid >> 6;
  int row0 = blockIdx.y * TM, col0 = blockIdx.x * 128;
  int wm = (wave >> 1) * (TM / 2), wn = (wave & 1) * 64;
  int mrow = lane & 15;
  int kq = lane >> 4;

  f32x4 acc[MI][4];
#pragma unroll
  for (int i = 0; i < MI; ++i)
#pragma unroll
    for (int j = 0; j < 4; ++j) acc[i][j] = (f32x4){0.f, 0.f, 0.f, 0.f};

  int kc = (tid & 3) * 8;
  const u16* Ag = A + (size_t)row0 * K;
  const u16* Bg = Bt + (size_t)col0 * K;

  for (int k0 = 0; k0 < K; k0 += 32) {
#pragma unroll
    for (int i = 0; i < TM / 64; ++i) {
      int u = i * 256 + tid;
      int rr = u >> 2;
      __builtin_amdgcn_global_load_lds(
          (const __attribute__((address_space(1))) u32*)(Ag + (size_t)rr * K + k0 + kc),
          (__attribute__((address_space(3))) u32*)(As + u * 8), 16, 0, 0);
    }
#pragma unroll
    for (int i = 0; i < 2; ++i) {
      int u = i * 256 + tid;
      int rr = u >> 2;
      __builtin_amdgcn_global_load_lds(
          (const __attribute__((address_space(1))) u32*)(Bg + (size_t)rr * K + k0 + kc),
          (__attribute__((address_space(3))) u32*)(Bs + u * 8), 16, 0, 0);
    }
    __syncthreads();
    bf16x8 af[MI], bfr[4];
#pragma unroll
    for (int mi = 0; mi < MI; ++mi)
      af[mi] = *(const bf16x8*)(As + (wm + mi * 16 + mrow) * 32 + kq * 8);
#pragma unroll
    for (int ni = 0; ni < 4; ++ni)
      bfr[ni] = *(const bf16x8*)(Bs + (wn + ni * 16 + mrow) * 32 + kq * 8);
#pragma unroll
    for (int mi = 0; mi < MI; ++mi)
#pragma unroll
      for (int ni = 0; ni < 4; ++ni)
        acc[mi][ni] = __builtin_amdgcn_mfma_f32_16x16x32_bf16(
            af[mi], bfr[ni], acc[mi][ni], 0, 0, 0);
    __syncthreads();
  }

  float* sred = (float*)Bs;  // 256 floats: [0..127]=sum, [128..255]=sumsq
  sred[tid] = 0.f;
  __syncthreads();
#pragma unroll
  for (int ni = 0; ni < 4; ++ni) {
    int col_l = wn + ni * 16 + mrow;
    int col = col0 + col_l;
    float s = 0.f, ss = 0.f;
#pragma unroll
    for (int mi = 0; mi < MI; ++mi) {
#pragma unroll
      for (int reg = 0; reg < 4; ++reg) {
        int row = row0 + wm + mi * 16 + kq * 4 + reg;
        float v = acc[mi][ni][reg];
        if (OUT_BF) {
          u16 hb = f2bf(v);
          v = bf2f(hb);
          ((u16*)Cout)[(size_t)row * N + col] = hb;
        } else {
          ((float*)Cout)[(size_t)row * N + col] = v;
        }
        s += v;
        ss += v * v;
      }
    }
    s += __shfl_xor(s, 16, 64);  s += __shfl_xor(s, 32, 64);
    ss += __shfl_xor(ss, 16, 64); ss += __shfl_xor(ss, 32, 64);
    if (kq == 0) {
      atomicAdd(&sred[col_l], s);
      atomicAdd(&sred[128 + col_l], ss);
    }
  }
  __syncthreads();
  if (tid < 128) {
    atomicAdd(&gsum[col0 + tid], sred[tid]);
    atomicAdd(&gsum[N + col0 + tid], sred[128 + tid]);
  }
}

// ---------------- BN (from raw sums) + relu, bf16 -> bf16, 8 elems/thread ------
__global__ __launch_bounds__(256) void bn_relu_bb_kernel(
    const uint4* __restrict__ X, const float* __restrict__ sums,
    uint4* __restrict__ out, int Cmask, int total8) {
  int i = blockIdx.x * 256 + threadIdx.x;
  if (i >= total8) return;
  uint4 v = X[i];
  int colb = (i << 3) & Cmask;
  int C = Cmask + 1;
  const float invB = 1.0f / B;
  u32 w[4] = {v.x, v.y, v.z, v.w};
  u32 o[4];
#pragma unroll
  for (int e = 0; e < 4; ++e) {
    int c0 = colb + e * 2, c1 = c0 + 1;
    float m0 = sums[c0] * invB, m1 = sums[c1] * invB;
    float i0 = rsqrtf(sums[C + c0] * invB - m0 * m0 + EPS);
    float i1 = rsqrtf(sums[C + c1] * invB - m1 * m1 + EPS);
    float x0 = bf2f((u16)(w[e] & 0xffffu));
    float x1 = bf2f((u16)(w[e] >> 16));
    x0 = fmaxf((x0 - m0) * i0, 0.f);
    x1 = fmaxf((x1 - m1) * i1, 0.f);
    o[e] = (u32)f2bf(x0) | ((u32)f2bf(x1) << 16);
  }
  out[i] = make_uint4(o[0], o[1], o[2], o[3]);
}

// ---------------- fused final: BN(z3 from sums) + relu + dot Wout + sigmoid ----
__global__ __launch_bounds__(256) void final_kernel(
    const float* __restrict__ cpart, const float* __restrict__ z3,
    const float* __restrict__ sums, const float* __restrict__ wout,
    float* __restrict__ out) {
  int r = blockIdx.x, tid = threadIdx.x;  // tid = column, N3 = 256
  const float invB = 1.0f / B;
  float m = sums[tid] * invB;
  float inv = rsqrtf(sums[N3 + tid] * invB - m * m + EPS);
  float x = fmaxf((z3[(size_t)r * N3 + tid] - m) * inv, 0.f) * wout[F + tid];
  for (int off = 32; off; off >>= 1) x += __shfl_down(x, off, 64);
  __shared__ float red[4];
  int lane = tid & 63, wid = tid >> 6;
  if (lane == 0) red[wid] = x;
  __syncthreads();
  if (tid == 0) {
    float s = cpart[r] + red[0] + red[1] + red[2] + red[3];
    out[r] = 1.0f / (1.0f + expf(-s));
  }
}

extern "C" void kernel_launch(void* const* d_in, const int* in_sizes, int n_in,
                              void* d_out, int out_size, void* d_ws,
                              size_t ws_size, hipStream_t stream) {
  const int* sparse = (const int*)d_in[0];
  const float* dense = (const float*)d_in[1];
  const float* ea = (const float*)d_in[2];
  const float* eb = (const float*)d_in[3];
  const float* ec = (const float*)d_in[4];
  const float* cw = (const float*)d_in[5];
  const float* cb = (const float*)d_in[6];
  const float* W1 = (const float*)d_in[7];
  const float* W2 = (const float*)d_in[9];
  const float* W3 = (const float*)d_in[11];
  const float* Wout = (const float*)d_in[13];
  float* out = (float*)d_out;

  float* ws = (float*)d_ws;
  size_t o = 0;
  float* h = ws + o;      o += (size_t)B * F;        // 56.5 MB fp32
  float* z3 = ws + o;     o += (size_t)B * N3;       //  8.4 MB fp32
  float* cpart = ws + o;  o += B;
  float* stats = ws + o;  o += 8192;                 // all atomic stat buffers
  float* sumsF = stats;            // 2*F  = 3450
  float* g1 = stats + 3456;        // 2*N1 = 2048
  float* g2 = stats + 5504;        // 2*N2 = 1024
  float* g3 = stats + 6528;        // 2*N3 = 512
  float* mi = ws + o;     o += 3456;                 // mean/inv for F
  float* consts = ws + o; o += 16;  o = (o + 7) & ~(size_t)7;
  u16* hbf = (u16*)(ws + o);  o += (size_t)B * KP1 / 2;
  u16* z1 = (u16*)(ws + o);   o += (size_t)B * N1 / 2;
  u16* z1n = (u16*)(ws + o);  o += (size_t)B * N1 / 2;
  u16* z2 = (u16*)(ws + o);   o += (size_t)B * N2 / 2;
  u16* z2n = (u16*)(ws + o);  o += (size_t)B * N2 / 2;
  u16* W1t = (u16*)(ws + o);  o += (size_t)N1 * KP1 / 2;
  u16* W2t = (u16*)(ws + o);  o += (size_t)N2 * N1 / 2;
  u16* W3t = (u16*)(ws + o);  o += (size_t)N3 * N2 / 2;

  // one memset clears every atomic accumulator
  hipMemsetAsync(stats, 0, 8192 * sizeof(float), stream);

  convw_all_kernel<<<2368, dim3(32, 8), 0, stream>>>(W1, W2, W3, W1t, W2t, W3t);

  gather_stats_kernel<<<B / GROWS, 256, 0, stream>>>(sparse, dense, ea, eb, ec,
                                                     h, sumsF);
  prep_kernel<<<1, 256, 0, stream>>>(sumsF, cw, cb, Wout, mi, consts);
  bnapply_gemv_kernel<<<B, 256, 0, stream>>>(h, mi, cw, Wout, consts,
                                             (u32*)hbf, cpart);

  gemm_bf16_kernel<true, 128><<<dim3(N1 / 128, B / 128), 256, 0, stream>>>(
      hbf, W1t, (void*)z1, g1, N1, KP1);
  bn_relu_bb_kernel<<<(B * N1 / 8 + 255) / 256, 256, 0, stream>>>(
      (const uint4*)z1, g1, (uint4*)z1n, N1 - 1, B * N1 / 8);

  gemm_bf16_kernel<true, 64><<<dim3(N2 / 128, B / 64), 256, 0, stream>>>(
      z1n, W2t, (void*)z2, g2, N2, N1);
  bn_relu_bb_kernel<<<(B * N2 / 8 + 255) / 256, 256, 0, stream>>>(
      (const uint4*)z2, g2, (uint4*)z2n, N2 - 1, B * N2 / 8);

  gemm_bf16_kernel<false, 64><<<dim3(N3 / 128, B / 64), 256, 0, stream>>>(
      z2n, W3t, (void*)z3, g3, N3, N2);

  final_kernel<<<B, 256, 0, stream>>>(cpart, z3, g3, Wout, out);
}